// Round 7
// baseline (2402.406 us; speedup 1.0000x reference)
//
#include <hip/hip_runtime.h>

#define B_ 128
#define T_ 2048
#define H_ 128
#define IN_ 6
#define CHUNK_ 32
#define NCHUNK_ 64
#define FLAG_STRIDE_ 64
#define HS_ 144
#define XGSLOT_ (CHUNK_ * 8192)   // 1 MiB of floats per ring slot
#define XGRING_ 2                 // depth-2 rings (24 rings x 2 MiB = 48 MiB)
#define NFLAGS_ 184  // fh 0..63 = l*32+sl (l<2); fx 64..87 = 64+gl*8+bg; fc 88..183 = 88+gl*32+sl

typedef _Float16 f16x8 __attribute__((ext_vector_type(8)));
typedef float    f32x4 __attribute__((ext_vector_type(4)));

__device__ __forceinline__ unsigned short f2h_u(float f) {
  union { _Float16 h; unsigned short u; } v; v.h = (_Float16)f; return v.u;
}
__device__ __forceinline__ unsigned int pack2(float a, float b) {
  return (unsigned int)f2h_u(a) | ((unsigned int)f2h_u(b) << 16);
}
__device__ __forceinline__ float sigf_(float x) {
  return __builtin_amdgcn_rcpf(1.0f + __expf(-x));
}
__device__ __forceinline__ float tanhf_(float x) {
  return 2.0f * __builtin_amdgcn_rcpf(1.0f + __expf(-2.0f * x)) - 1.0f;
}
__device__ __forceinline__ f16x8 load_w8(const float* __restrict__ p) {
  f16x8 r;
#pragma unroll
  for (int i = 0; i < 8; ++i) r[i] = (_Float16)p[i];
  return r;
}

__global__ void init_flags(unsigned int* flags) {
  flags[blockIdx.x * 256 + threadIdx.x] = 0u;  // grid 46 -> 11776 = 184 * 64
}

#define BARRIER_LGKM()                                              \
  do {                                                              \
    asm volatile("s_waitcnt lgkmcnt(0)" ::: "memory");              \
    __builtin_amdgcn_s_barrier();                                   \
    __builtin_amdgcn_sched_barrier(0);                              \
  } while (0)

#define PUBLISH_FENCE()                                             \
  do {                                                              \
    asm volatile("s_waitcnt vmcnt(0)" ::: "memory");                \
    __builtin_amdgcn_s_barrier();                                   \
  } while (0)

#define MFMA16(A, B, C) __builtin_amdgcn_mfma_f32_16x16x32_f16((A), (B), (C), 0, 0, 0)

// ---------------------------------------------------------------------------
// R19: alternating half-window recurrence + layer-0 input-GEMM offload.
//  - 96 rec WGs (layer=bid>>5, sl=bid&31, batch-4). Groups A={b0,b1} B={b2,b3}
//    (mirror-8 cols). Half-window (g,t): barrier; read h_g(t-1); 16 MFMA(g,t);
//    INTERLEAVED act of other group's pending acc (independent -> hides under
//    the 620cy MFMA pipe) + h-write + region/xg traffic. 4096 halves.
//  - Layer 0's xg0 = bias + Wih0.x produced by 8 new dependency-free producer
//    WGs (bit-identical math to the old fused wx MFMA); all rec layers uniform.
//  - xg rings depth 2 (ws unchanged ~113MB). Producers gl=1,2 as R16.
// ---------------------------------------------------------------------------
__global__ __launch_bounds__(512, 2)
void lstm_pipe(const float* __restrict__ x,
               const float* __restrict__ Wih0, const float* __restrict__ Whh0,
               const float* __restrict__ bih0, const float* __restrict__ bhh0,
               const float* __restrict__ Wih1, const float* __restrict__ Whh1,
               const float* __restrict__ bih1, const float* __restrict__ bhh1,
               const float* __restrict__ Wih2, const float* __restrict__ Whh2,
               const float* __restrict__ bih2, const float* __restrict__ bhh2,
               unsigned short* __restrict__ region,   // f16 [B][T][128]
               float* __restrict__ xg,                // 24 rings [gl*8+bg][2][XGSLOT_]
               unsigned int* __restrict__ state_h,    // [B][64] f16x2
               unsigned int* __restrict__ flags)
{
  const int bid  = blockIdx.x;
  const int tid  = threadIdx.x;
  const int lane = tid & 63;
  const int wv   = tid >> 6;    // wave 0..7
  const int n16  = lane & 15;
  const int quad = lane >> 4;

  __shared__ unsigned short smem[32 * 16 * HS_];   // 147456 B (producer max)
  __shared__ int s_have;

#define WAITP(ptr_, need_, have_)                                   \
  do {                                                              \
    if ((have_) < (need_)) {                                        \
      if (tid == 0) {                                               \
        int v = (int)__hip_atomic_load(ptr_, __ATOMIC_RELAXED,      \
                                       __HIP_MEMORY_SCOPE_AGENT);   \
        while (v < (need_)) {                                       \
          __builtin_amdgcn_s_sleep(2);                              \
          v = (int)__hip_atomic_load(ptr_, __ATOMIC_RELAXED,        \
                                     __HIP_MEMORY_SCOPE_AGENT);     \
        }                                                           \
        (void)__hip_atomic_load(ptr_, __ATOMIC_ACQUIRE,             \
                                __HIP_MEMORY_SCOPE_AGENT);          \
        s_have = v;                                                 \
      }                                                             \
      __syncthreads();                                              \
      (have_) = s_have;                                             \
    }                                                               \
  } while (0)

  if (bid >= 96) {
    // ======================= producer roles ==============================
    const int gi = bid - 96;
    const int gl = gi >> 3;        // 0,1,2 : produces xg for layer gl
    const int bg = gi & 7;
    float* xgo = xg + (size_t)(gl * 8 + bg) * (XGRING_ * (size_t)XGSLOT_);
    unsigned int* fx_out = &flags[(64 + gl * 8 + bg) * FLAG_STRIDE_];
    unsigned int* fcp[4];
#pragma unroll
    for (int q = 0; q < 4; ++q)
      fcp[q] = &flags[(88 + gl * 32 + 4 * bg + q) * FLAG_STRIDE_];

    if (gl == 0) {
      // ---- layer-0 input GEMM: xg0 = bias0 + Wih0 . x (no upstream dep) ----
      f16x8 wih[4];
#pragma unroll
      for (int j = 0; j < 4; ++j)
#pragma unroll
        for (int i = 0; i < 8; ++i) wih[j][i] = (_Float16)0.f;
      if (quad == 0) {
#pragma unroll
        for (int j = 0; j < 4; ++j) {
          const float* p = Wih0 + (size_t)(j * 128 + 16 * wv + n16) * IN_;
#pragma unroll
          for (int i = 0; i < IN_; ++i) wih[j][i] = (_Float16)p[i];
        }
      }
      f32x4 bias4[4];
#pragma unroll
      for (int j = 0; j < 4; ++j)
#pragma unroll
        for (int r = 0; r < 4; ++r) {
          int row = j * 128 + 16 * wv + quad * 4 + r;
          bias4[j][r] = bih0[row] + bhh0[row];
        }
      unsigned short* xbp = smem;                 // [32 t][16 b][8]
      const int tt = tid >> 4, bb = tid & 15;
      int hc0 = 0, hc1 = 0, hc2 = 0, hc3 = 0;
      for (int k = 0; k < NCHUNK_; ++k) {
        if (k >= XGRING_) {
          WAITP(fcp[0], k - (XGRING_ - 1), hc0);
          WAITP(fcp[1], k - (XGRING_ - 1), hc1);
          WAITP(fcp[2], k - (XGRING_ - 1), hc2);
          WAITP(fcp[3], k - (XGRING_ - 1), hc3);
        }
        {
          const float* xp = x + ((size_t)(bg * 16 + bb) * T_ + (size_t)(CHUNK_ * k + tt)) * IN_;
          uint4 v;
          v.x = pack2(xp[0], xp[1]); v.y = pack2(xp[2], xp[3]);
          v.z = pack2(xp[4], xp[5]); v.w = 0u;
          *(uint4*)&xbp[(tt * 16 + bb) * 8] = v;
        }
        __syncthreads();
        const int slot = k & 1;
        for (int t = 0; t < CHUNK_; ++t) {
          f16x8 xi;
#pragma unroll
          for (int i = 0; i < 8; ++i) xi[i] = (_Float16)0.f;
          if (quad == 0) xi = *(const f16x8*)&xbp[(t * 16 + n16) * 8];
          float* xp = xgo + (size_t)(slot * CHUNK_ + t) * 8192 + quad * 64 + n16 * 4;
#pragma unroll
          for (int j = 0; j < 4; ++j) {
            f32x4 a = MFMA16(wih[j], xi, bias4[j]);
            *(f32x4*)(xp + (size_t)(8 * j + wv) * 256) = a;
          }
        }
        __syncthreads();
        if (tid == 0)
          __hip_atomic_store(fx_out, (unsigned int)(k + 1),
                             __ATOMIC_RELEASE, __HIP_MEMORY_SCOPE_AGENT);
      }
      return;
    }

    // ---- gl = 1,2 : hidden-state GEMM producers (R16-proven, depth-2 ring) ----
    const int b8 = n16 & 7;
    const float* Wih = (gl == 1) ? Wih1 : Wih2;
    const float* bih = (gl == 1) ? bih1 : bih2;
    const float* bhh = (gl == 1) ? bhh1 : bhh2;
    unsigned int* fhp[4];
#pragma unroll
    for (int q = 0; q < 4; ++q)
      fhp[q] = &flags[((gl - 1) * 32 + 4 * bg + q) * FLAG_STRIDE_];

    f16x8 wih[4][4];
#pragma unroll
    for (int j = 0; j < 4; ++j)
#pragma unroll
      for (int kc = 0; kc < 4; ++kc)
        wih[j][kc] = load_w8(Wih + (size_t)(j * 128 + 16 * wv + n16) * H_ + kc * 32 + quad * 8);
    f32x4 bias4[4];
#pragma unroll
    for (int j = 0; j < 4; ++j)
#pragma unroll
      for (int r = 0; r < 4; ++r) {
        int row = j * 128 + 16 * wv + quad * 4 + r;
        bias4[j][r] = bih[row] + bhh[row];
      }

    int hh0 = 0, hh1 = 0, hh2 = 0, hh3 = 0;
    int hc0 = 0, hc1 = 0, hc2 = 0, hc3 = 0;
    const int tt = tid >> 4, bb = tid & 15;
    const int swk = bb & 7;
    for (int k = 0; k < NCHUNK_; ++k) {
      WAITP(fhp[0], k + 1, hh0);
      WAITP(fhp[1], k + 1, hh1);
      WAITP(fhp[2], k + 1, hh2);
      WAITP(fhp[3], k + 1, hh3);
      if (k >= XGRING_) {
        WAITP(fcp[0], k - (XGRING_ - 1), hc0);
        WAITP(fcp[1], k - (XGRING_ - 1), hc1);
        WAITP(fcp[2], k - (XGRING_ - 1), hc2);
        WAITP(fcp[3], k - (XGRING_ - 1), hc3);
      }
      {
        const uint4* gp = (const uint4*)(region +
            ((size_t)(bg * 16 + bb) * T_ + (size_t)(CHUNK_ * k + tt)) * H_);
        uint4* lp = (uint4*)&smem[(tt * 16 + bb) * HS_];
#pragma unroll
        for (int i = 0; i < 16; ++i) lp[i ^ swk] = gp[i];
      }
      __syncthreads();
      const int slot = k & 1;
      for (int t = 0; t < CHUNK_; ++t) {
        f16x8 hi4[4];
#pragma unroll
        for (int kc = 0; kc < 4; ++kc)
          hi4[kc] = *(const f16x8*)&smem[(t * 16 + n16) * HS_ +
                                         ((kc * 32 + quad * 8) ^ (b8 << 3))];
        float* xp = xgo + (size_t)(slot * CHUNK_ + t) * 8192 + quad * 64 + n16 * 4;
#pragma unroll
        for (int j = 0; j < 4; ++j) {
          f32x4 a = bias4[j];
#pragma unroll
          for (int kc = 0; kc < 4; ++kc)
            a = MFMA16(wih[j][kc], hi4[kc], a);
          *(f32x4*)(xp + (size_t)(8 * j + wv) * 256) = a;
        }
      }
      __syncthreads();
      if (tid == 0)
        __hip_atomic_store(fx_out, (unsigned int)(k + 1),
                           __ATOMIC_RELEASE, __HIP_MEMORY_SCOPE_AGENT);
    }
    return;
  }

  // ========================= recurrence role =============================
  const int layer = bid >> 5;
  const int sl    = bid & 31;
  const int bcol1 = n16 & 1;            // batch within group
  const int rr    = (n16 >> 1) & 3;     // owned acc row
  const bool actv = (n16 < 8);          // acting lanes (mirror-8 dedup)
  const bool r1 = (rr & 1) != 0, r2 = (rr & 2) != 0;
  const int hidx = 16 * wv + 4 * quad + rr;
  const int bA = sl * 4 + bcol1;
  const int bB = sl * 4 + 2 + bcol1;
  const float* Whh = (layer == 0) ? Whh0 : ((layer == 1) ? Whh1 : Whh2);

  unsigned short* hstate = smem;        // [2 groups][2 batches][HS_]

  f16x8 whh[4][4];
#pragma unroll
  for (int j = 0; j < 4; ++j)
#pragma unroll
    for (int kc = 0; kc < 4; ++kc)
      whh[j][kc] = load_w8(Whh + (size_t)(j * 128 + 16 * wv + n16) * H_ + kc * 32 + quad * 8);

  for (int i = tid; i < (4 * HS_) / 2; i += 512) ((unsigned int*)smem)[i] = 0u;

  const float* xgi = xg + (size_t)(layer * 8 + (sl >> 2)) * (XGRING_ * (size_t)XGSLOT_);
  const int laneA = wv * 256 + quad * 64 + ((sl & 3) * 4 + 0 + bcol1) * 4;
  const int laneB = wv * 256 + quad * 64 + ((sl & 3) * 4 + 2 + bcol1) * 4;
  unsigned int* fx_in  = &flags[(64 + layer * 8 + (sl >> 2)) * FLAG_STRIDE_];
  unsigned int* fc_out = &flags[(88 + layer * 32 + sl) * FLAG_STRIDE_];
  unsigned int* fh_out = (layer < 2) ? &flags[(layer * 32 + sl) * FLAG_STRIDE_] : nullptr;
  unsigned short* regA = region + (size_t)bA * T_ * H_ + hidx;
  unsigned short* regB = region + (size_t)bB * T_ * H_ + hidx;

  float cA = 0.f, cB = 0.f;
  f32x4 accP0 = {0,0,0,0}, accP1 = {0,0,0,0}, accP2 = {0,0,0,0}, accP3 = {0,0,0,0};
  f32x4 xrA[4], xrB[4];
  unsigned short dhA[8], dhB[8];
  int slotA = 0, slotB = 0;
  int have_x = 0;

#define SEL3(a_) (r1 ? (r2 ? (a_)[3] : (a_)[1]) : (r2 ? (a_)[2] : (a_)[0]))
#define ACT1(aP0_, aP1_, aP2_, aP3_, c_, uh_)                        \
  do {                                                               \
    float vi = SEL3(aP0_), vf = SEL3(aP1_);                          \
    float vg = SEL3(aP2_), vo = SEL3(aP3_);                          \
    float i_ = sigf_(vi), f_ = sigf_(vf);                            \
    float t_ = tanhf_(vg), o_ = sigf_(vo);                           \
    (c_) = f_ * (c_) + i_ * t_;                                      \
    (uh_) = f2h_u(o_ * tanhf_(c_));                                  \
  } while (0)

  // prologue: first xg loads for both groups at t=0 (slot 0)
  WAITP(fx_in, 1, have_x);
#pragma unroll
  for (int j = 0; j < 4; ++j) {
    xrA[j] = *(const f32x4*)(xgi + (size_t)j * 2048 + laneA);
    xrB[j] = *(const f32x4*)(xgi + (size_t)j * 2048 + laneB);
  }
  __syncthreads();  // hstate zeros visible

  for (int gg = 0; gg < 256; ++gg) {
#pragma unroll
    for (int s = 0; s < 8; ++s) {
      const int p = 8 * gg + s;
      // ================= A-half: MFMA(A,p) || act B(p-1) =================
      BARRIER_LGKM();
      f16x8 hA0 = *(const f16x8*)&hstate[(0 * 2 + bcol1) * HS_ + 0 * 32 + quad * 8];
      f16x8 hA1 = *(const f16x8*)&hstate[(0 * 2 + bcol1) * HS_ + 1 * 32 + quad * 8];
      f16x8 hA2 = *(const f16x8*)&hstate[(0 * 2 + bcol1) * HS_ + 2 * 32 + quad * 8];
      f16x8 hA3 = *(const f16x8*)&hstate[(0 * 2 + bcol1) * HS_ + 3 * 32 + quad * 8];
      // act B(p-1): independent of the MFMAs below -> scheduler interleaves
      if (gg > 0 || s > 0) {
        unsigned short uh;
        ACT1(accP0, accP1, accP2, accP3, cB, uh);
        if (actv) hstate[(1 * 2 + bcol1) * HS_ + hidx] = uh;   // ds_write_b16
        dhB[(s == 0) ? 7 : (s - 1)] = uh;
        if (s == 0 && layer < 2 && actv) {   // flush B steps p-8..p-1
#pragma unroll
          for (int k = 0; k < 8; ++k) regB[(size_t)(p - 8 + k) * H_] = dhB[k];
        }
      }
      // MFMA A(p)
      f32x4 aN0 = MFMA16(whh[0][0], hA0, xrA[0]);
      f32x4 aN1 = MFMA16(whh[1][0], hA0, xrA[1]);
      f32x4 aN2 = MFMA16(whh[2][0], hA0, xrA[2]);
      f32x4 aN3 = MFMA16(whh[3][0], hA0, xrA[3]);
      aN0 = MFMA16(whh[0][1], hA1, aN0); aN1 = MFMA16(whh[1][1], hA1, aN1);
      aN2 = MFMA16(whh[2][1], hA1, aN2); aN3 = MFMA16(whh[3][1], hA1, aN3);
      aN0 = MFMA16(whh[0][2], hA2, aN0); aN1 = MFMA16(whh[1][2], hA2, aN1);
      aN2 = MFMA16(whh[2][2], hA2, aN2); aN3 = MFMA16(whh[3][2], hA2, aN3);
      aN0 = MFMA16(whh[0][3], hA3, aN0); aN1 = MFMA16(whh[1][3], hA3, aN1);
      aN2 = MFMA16(whh[2][3], hA3, aN2); aN3 = MFMA16(whh[3][3], hA3, aN3);
      // A-side prefetch for t=p+1 (chunk crossing handled here for both groups)
      if (s == 7 && (gg & 3) == 3 && gg != 255)
        WAITP(fx_in, ((gg + 1) >> 2) + 1, have_x);
      if (p < 2047) {
        const int tn = p + 1;
        if ((tn & 31) == 0) slotA ^= 1;
        const float* pA = xgi + (size_t)slotA * XGSLOT_ + (size_t)(tn & 31) * 8192 + laneA;
#pragma unroll
        for (int j = 0; j < 4; ++j) xrA[j] = *(const f32x4*)(pA + (size_t)j * 2048);
      }
      // publish chunk (both groups complete through step 32c+31 at this point)
      if (s == 0 && (gg & 3) == 0 && gg > 0) {
        PUBLISH_FENCE();
        if (tid == 0) {
          unsigned int cdone = (unsigned int)(gg >> 2);
          if (layer < 2)
            __hip_atomic_store(fh_out, cdone, __ATOMIC_RELEASE, __HIP_MEMORY_SCOPE_AGENT);
          __hip_atomic_store(fc_out, cdone, __ATOMIC_RELEASE, __HIP_MEMORY_SCOPE_AGENT);
        }
      }
      // ================= B-half: MFMA(B,p) || act A(p) ===================
      BARRIER_LGKM();
      f16x8 hB0 = *(const f16x8*)&hstate[(1 * 2 + bcol1) * HS_ + 0 * 32 + quad * 8];
      f16x8 hB1 = *(const f16x8*)&hstate[(1 * 2 + bcol1) * HS_ + 1 * 32 + quad * 8];
      f16x8 hB2 = *(const f16x8*)&hstate[(1 * 2 + bcol1) * HS_ + 2 * 32 + quad * 8];
      f16x8 hB3 = *(const f16x8*)&hstate[(1 * 2 + bcol1) * HS_ + 3 * 32 + quad * 8];
      {
        unsigned short uh;
        ACT1(aN0, aN1, aN2, aN3, cA, uh);
        if (actv) hstate[(0 * 2 + bcol1) * HS_ + hidx] = uh;
        dhA[s] = uh;
        if (s == 7 && layer < 2 && actv) {   // flush A steps p-7..p
#pragma unroll
          for (int k = 0; k < 8; ++k) regA[(size_t)(p - 7 + k) * H_] = dhA[k];
        }
      }
      accP0 = MFMA16(whh[0][0], hB0, xrB[0]);
      accP1 = MFMA16(whh[1][0], hB0, xrB[1]);
      accP2 = MFMA16(whh[2][0], hB0, xrB[2]);
      accP3 = MFMA16(whh[3][0], hB0, xrB[3]);
      accP0 = MFMA16(whh[0][1], hB1, accP0); accP1 = MFMA16(whh[1][1], hB1, accP1);
      accP2 = MFMA16(whh[2][1], hB1, accP2); accP3 = MFMA16(whh[3][1], hB1, accP3);
      accP0 = MFMA16(whh[0][2], hB2, accP0); accP1 = MFMA16(whh[1][2], hB2, accP1);
      accP2 = MFMA16(whh[2][2], hB2, accP2); accP3 = MFMA16(whh[3][2], hB2, accP3);
      accP0 = MFMA16(whh[0][3], hB3, accP0); accP1 = MFMA16(whh[1][3], hB3, accP1);
      accP2 = MFMA16(whh[2][3], hB3, accP2); accP3 = MFMA16(whh[3][3], hB3, accP3);
      if (p < 2047) {
        const int tn = p + 1;
        if ((tn & 31) == 0) slotB ^= 1;
        const float* pB = xgi + (size_t)slotB * XGSLOT_ + (size_t)(tn & 31) * 8192 + laneB;
#pragma unroll
        for (int j = 0; j < 4; ++j) xrB[j] = *(const f32x4*)(pB + (size_t)j * 2048);
      }
    }
  }
  // epilogue: act B(2047), final flushes, state_h, final publish
  {
    unsigned short uh;
    ACT1(accP0, accP1, accP2, accP3, cB, uh);
    dhB[7] = uh;
    if (layer < 2 && actv) {
#pragma unroll
      for (int k = 0; k < 8; ++k) regB[(size_t)(2040 + k) * H_] = dhB[k];
    }
    if (layer == 2 && actv) {
      ((unsigned short*)state_h)[(size_t)bA * 128 + hidx] = dhA[7];
      ((unsigned short*)state_h)[(size_t)bB * 128 + hidx] = dhB[7];
    }
  }
  PUBLISH_FENCE();
  if (tid == 0) {
    if (layer < 2)
      __hip_atomic_store(fh_out, 64u, __ATOMIC_RELEASE, __HIP_MEMORY_SCOPE_AGENT);
    __hip_atomic_store(fc_out, 64u, __ATOMIC_RELEASE, __HIP_MEMORY_SCOPE_AGENT);
  }
#undef SEL3
#undef ACT1
#undef WAITP
}

// ---------------------------------------------------------------------------
__global__ void head_kernel(const unsigned int* __restrict__ state_h,
                            const float* __restrict__ Wout,
                            const float* __restrict__ bout,
                            float* __restrict__ out)
{
  int b = threadIdx.x;  // 128 threads, 1 block
  float s = bout[0];
  for (int j = 0; j < 64; ++j) {
    unsigned int p = state_h[b * 64 + j];
    union { unsigned short u; _Float16 h; } lo, hi;
    lo.u = (unsigned short)(p & 0xffffu);
    hi.u = (unsigned short)(p >> 16);
    s += (float)lo.h * Wout[2 * j] + (float)hi.h * Wout[2 * j + 1];
  }
  out[b] = s;
}

// ---------------------------------------------------------------------------
extern "C" void kernel_launch(void* const* d_in, const int* in_sizes, int n_in,
                              void* d_out, int out_size, void* d_ws, size_t ws_size,
                              hipStream_t stream)
{
  const float* x = (const float*)d_in[0];
  const float* Wih[3] = {(const float*)d_in[1], (const float*)d_in[5], (const float*)d_in[9]};
  const float* Whh[3] = {(const float*)d_in[2], (const float*)d_in[6], (const float*)d_in[10]};
  const float* bih[3] = {(const float*)d_in[3], (const float*)d_in[7], (const float*)d_in[11]};
  const float* bhh[3] = {(const float*)d_in[4], (const float*)d_in[8], (const float*)d_in[12]};
  const float* Wout = (const float*)d_in[13];
  const float* bout = (const float*)d_in[14];
  float* out = (float*)d_out;

  char* ws = (char*)d_ws;
  size_t off = 0;
  unsigned short* region = (unsigned short*)(ws + off); off += (size_t)B_ * T_ * H_ * 2;            // 64 MiB
  float* xg = (float*)(ws + off);                       off += (size_t)24 * XGRING_ * XGSLOT_ * 4;  // 48 MiB
  unsigned int* state_h  = (unsigned int*)(ws + off);   off += (size_t)B_ * 64 * 4;
  off = (off + 255) & ~(size_t)255;
  unsigned int* flags    = (unsigned int*)(ws + off);   off += NFLAGS_ * FLAG_STRIDE_ * 4;

  init_flags<<<46, 256, 0, stream>>>(flags);
  lstm_pipe<<<120, 512, 0, stream>>>(x,
      Wih[0], Whh[0], bih[0], bhh[0],
      Wih[1], Whh[1], bih[1], bhh[1],
      Wih[2], Whh[2], bih[2], bhh[2],
      region, xg, state_h, flags);
  head_kernel<<<1, 128, 0, stream>>>(state_h, Wout, bout, out);
}